// Round 13
// baseline (166.825 us; speedup 1.0000x reference)
//
#include <hip/hip_runtime.h>
#include <hip/hip_fp16.h>
#include <math.h>

// ---------------------------------------------------------------------------
// GCN 2-layer, bucket-partitioned CSR build + wide-parallel fp16 gathers.
// R13: dynamic run reservation (global cursor atomics) replaces the whole
// k1a/kscan1 offset-precompute front end; k2 reads staging once into regs.
// Pipeline: memset(cursors) -> k1b_fat(scatter||gemm) -> k2 -> g1 -> g2.
// ---------------------------------------------------------------------------

#define BSH 9
#define BNODES 512
#define P1 512
#define GROWS 64     // gemm rows per block
#define K2BUF 10240  // k2 LDS sort buffer entries
#define BCAP 12288   // per-bucket staging/csr capacity (mean 8163, +45 sigma)
#define EPT 16       // max edges per thread in k1b register cache
#define EPT2 12      // max edges per thread in k2 register cache (12288/1024)
#define CSTR 16      // cursor stride in ints (64B line padding)

struct alignas(8) Half4 { __half x, y, z, w; };

// ---- k1b FAT: [reg-cached LDS-sorted scatter, dynamic runs] || [gemm1] ----
__global__ void k1b_fat(const int* __restrict__ src, const int* __restrict__ dst,
                        int* __restrict__ cursor,
                        unsigned int* __restrict__ staging,
                        const float* __restrict__ x, const float* __restrict__ W1,
                        Half4* __restrict__ g1h, int NBK, int n, int E) {
    __shared__ float sx[GROWS * 132];   // 33792 B; scatter branch aliases as int[]
    __shared__ float4 sW4[512];         // 8192 B: W1 [128][16] as [k][c4]
    int b = blockIdx.x;
    if (b < P1) {
        // layout in sx (8448 ints): hist | cs | rbase | cur | buf | gaddr
        int* hist  = (int*)sx;          // [256] per-bucket count in this slice
        int* cs    = hist + 256;        // [256] within-block exclusive offsets
        int* rbase = hist + 512;        // [256] global run base (from cursor)
        int* cur   = hist + 768;        // [256] placement tickets
        int* buf   = hist + 1024;       // [3200] sorted packed values
        int* gaddr = buf + 3200;        // [3200] sorted global addresses (-1=drop)
        int t = threadIdx.x;
        hist[t] = 0; cur[t] = 0;
        __syncthreads();
        int slice = (E + P1 - 1) / P1;
        int e0 = b * slice, e1 = min(E, e0 + slice);
        int len = e1 - e0;
        // single global read into registers
        int dl[EPT], sl[EPT];
        int cnt = 0;
        for (int e = e0 + t; e < e1 && cnt < EPT; e += 256, ++cnt) {
            dl[cnt] = dst[e];
            sl[cnt] = src[e];
        }
        for (int i = 0; i < cnt; ++i)
            atomicAdd(&hist[dl[i] >> BSH], 1);
        __syncthreads();
        // exclusive scan hist[0..256) -> cs; reserve global run per bucket
        int h = hist[t];
        cs[t] = h;
        __syncthreads();
        for (int o = 1; o < 256; o <<= 1) {
            int add = (t >= o) ? cs[t - o] : 0;
            __syncthreads();
            cs[t] += add;
            __syncthreads();
        }
        int incl = cs[t];
        __syncthreads();
        cs[t] = incl - h;  // exclusive
        rbase[t] = (h > 0 && t < NBK) ? atomicAdd(&cursor[t * CSTR], h) : 0;
        __syncthreads();
        // place into LDS bucket-sorted; compute global addresses
        for (int i = 0; i < cnt; ++i) {
            int d = dl[i], s = sl[i];
            int k = d >> BSH;
            int tk = atomicAdd(&cur[k], 1);
            int pos = cs[k] + tk;
            buf[pos] = (s << BSH) | (d & (BNODES - 1));
            int g = rbase[k] + tk;
            gaddr[pos] = (g < BCAP) ? (k * BCAP + g) : -1;  // overflow guard
        }
        __syncthreads();
        // coalesced copy-out: consecutive lanes -> consecutive run addresses
        for (int p = t; p < len; p += 256) {
            int a = gaddr[p];
            if (a >= 0) staging[a] = (unsigned int)buf[p];
        }
    } else {
        int t = threadIdx.x;
        int base = (b - P1) * GROWS;
        for (int i = t; i < 512; i += 256) sW4[i] = ((const float4*)W1)[i];
        for (int i = t; i < GROWS * 32; i += 256) {
            int r = i >> 5, c = i & 31;
            int row = base + r;
            float4 v = (row < n) ? ((const float4*)x)[(size_t)row * 32 + c]
                                 : make_float4(0.f, 0.f, 0.f, 0.f);
            *((float4*)&sx[r * 132 + c * 4]) = v;
        }
        __syncthreads();
        int r = t >> 2, c4 = t & 3;
        int row = base + r;
        if (row >= n) return;
        float4 acc = make_float4(0.f, 0.f, 0.f, 0.f);
        #pragma unroll 8
        for (int q = 0; q < 32; ++q) {
            float4 xv = *((const float4*)&sx[r * 132 + q * 4]);
            #pragma unroll
            for (int j = 0; j < 4; ++j) {
                float s = (j == 0) ? xv.x : (j == 1) ? xv.y : (j == 2) ? xv.z : xv.w;
                float4 w = sW4[(q * 4 + j) * 4 + c4];
                acc.x += s * w.x; acc.y += s * w.y; acc.z += s * w.z; acc.w += s * w.w;
            }
        }
        Half4 hh;
        hh.x = __float2half(acc.x); hh.y = __float2half(acc.y);
        hh.z = __float2half(acc.z); hh.w = __float2half(acc.w);
        g1h[(size_t)row * 4 + c4] = hh;   // unscaled; k2 applies dinv
    }
}

// ---- k2: per-bucket CSR (reg-cached, LDS-sorted, contiguous out) + meta ----
__global__ void __launch_bounds__(1024) k2_bucket(
        const unsigned int* __restrict__ staging, const int* __restrict__ cursor,
        int* __restrict__ csr, int* __restrict__ deg, float* __restrict__ dinv,
        int* __restrict__ row_start, Half4* __restrict__ g1h, int n) {
    __shared__ int lh[BNODES], sc[BNODES], lcur[BNODES];
    __shared__ float ldv[BNODES];
    __shared__ int buf[K2BUF];
    int kb = blockIdx.x, t = threadIdx.x;
    int node0 = kb << BSH;
    int nloc = min(BNODES, n - node0);
    int ebase = kb * BCAP;
    int ecnt = min(cursor[kb * CSTR], BCAP);
    if (t < BNODES) { lh[t] = 0; lcur[t] = 0; }
    __syncthreads();
    // single global read into registers
    int el[EPT2];
    int cnt = 0;
    for (int e = t; e < ecnt && cnt < EPT2; e += 1024, ++cnt)
        el[cnt] = (int)staging[ebase + e];
    for (int i = 0; i < cnt; ++i)
        atomicAdd(&lh[el[i] & (BNODES - 1)], 1);
    __syncthreads();
    int own = 0;
    if (t < BNODES) { own = lh[t]; sc[t] = own; }
    __syncthreads();
    for (int o = 1; o < BNODES; o <<= 1) {   // inclusive scan over 512
        int add = 0;
        if (t < BNODES && t >= o) add = sc[t - o];
        __syncthreads();
        if (t < BNODES) sc[t] += add;
        __syncthreads();
    }
    if (t < BNODES) {
        int excl = sc[t] - own;
        if (t < nloc) {
            deg[node0 + t] = own;
            row_start[node0 + t] = ebase + excl;
            float dv = rsqrtf((float)(own + 1));  // +1 self-loop
            dinv[node0 + t] = dv;
            ldv[t] = dv;
        }
        sc[t] = excl;
    }
    __syncthreads();
    if (ecnt <= K2BUF) {
        for (int i = 0; i < cnt; ++i) {
            int p = el[i];
            int loc = p & (BNODES - 1);
            int tk = atomicAdd(&lcur[loc], 1);
            buf[sc[loc] + tk] = p >> BSH;
        }
        __syncthreads();
        for (int p = t; p < ecnt; p += 1024)
            csr[ebase + p] = buf[p];
    } else {  // statistically unreachable fallback: scattered direct place
        for (int i = 0; i < cnt; ++i) {
            int p = el[i];
            int loc = p & (BNODES - 1);
            int tk = atomicAdd(&lcur[loc], 1);
            csr[ebase + sc[loc] + tk] = p >> BSH;
        }
    }
    for (int j = t; j < nloc * 4; j += 1024) {
        float dv = ldv[j >> 2];
        Half4 v = g1h[(size_t)node0 * 4 + j];
        v.x = __float2half(__half2float(v.x) * dv);
        v.y = __float2half(__half2float(v.y) * dv);
        v.z = __float2half(__half2float(v.z) * dv);
        v.w = __float2half(__half2float(v.w) * dv);
        g1h[(size_t)node0 * 4 + j] = v;
    }
}

// ---- gather1: 16 lanes/node, 32B msg per lane-edge, tree-halving reduce ----
__global__ void k_gather1(const uint4* __restrict__ g1q, const int* __restrict__ csr,
                          const int* __restrict__ row_start, const int* __restrict__ deg,
                          const float* __restrict__ dinv, const float* __restrict__ b1,
                          const float* __restrict__ W2, Half4* __restrict__ g2h, int n) {
    int idx = blockIdx.x * 256 + threadIdx.x;
    int i = idx >> 4, l = idx & 15;
    if (i >= n) return;
    int off = row_start[i], dg = deg[i];
    float acc[16];
    #pragma unroll
    for (int j = 0; j < 16; ++j) acc[j] = 0.f;
    if (l == 0) {   // self-loop term (32 B = g1q[2i], g1q[2i+1])
        uint4 p0 = g1q[2 * (size_t)i], p1 = g1q[2 * (size_t)i + 1];
        const __half2* h0 = reinterpret_cast<const __half2*>(&p0);
        const __half2* h1 = reinterpret_cast<const __half2*>(&p1);
        #pragma unroll
        for (int j = 0; j < 4; ++j) {
            float2 f0 = __half22float2(h0[j]);
            float2 f1 = __half22float2(h1[j]);
            acc[2 * j] += f0.x; acc[2 * j + 1] += f0.y;
            acc[8 + 2 * j] += f1.x; acc[9 + 2 * j] += f1.y;
        }
    }
    for (int k = l; k < dg; k += 16) {
        int s = csr[off + k];
        uint4 p0 = g1q[2 * (size_t)s], p1 = g1q[2 * (size_t)s + 1];
        const __half2* h0 = reinterpret_cast<const __half2*>(&p0);
        const __half2* h1 = reinterpret_cast<const __half2*>(&p1);
        #pragma unroll
        for (int j = 0; j < 4; ++j) {
            float2 f0 = __half22float2(h0[j]);
            float2 f1 = __half22float2(h1[j]);
            acc[2 * j] += f0.x; acc[2 * j + 1] += f0.y;
            acc[8 + 2 * j] += f1.x; acc[9 + 2 * j] += f1.y;
        }
    }
    // tree-halving cross-lane reduce
    #pragma unroll
    for (int j = 0; j < 8; ++j) {
        float send = (l & 1) ? acc[j] : acc[j + 8];
        float recv = __shfl_xor(send, 1);
        acc[j] = ((l & 1) ? acc[j + 8] : acc[j]) + recv;
    }
    #pragma unroll
    for (int j = 0; j < 4; ++j) {
        float send = (l & 2) ? acc[j] : acc[j + 4];
        float recv = __shfl_xor(send, 2);
        acc[j] = ((l & 2) ? acc[j + 4] : acc[j]) + recv;
    }
    #pragma unroll
    for (int j = 0; j < 2; ++j) {
        float send = (l & 4) ? acc[j] : acc[j + 2];
        float recv = __shfl_xor(send, 4);
        acc[j] = ((l & 4) ? acc[j + 2] : acc[j]) + recv;
    }
    {
        float send = (l & 8) ? acc[0] : acc[1];
        float recv = __shfl_xor(send, 8);
        acc[0] = ((l & 8) ? acc[1] : acc[0]) + recv;
    }
    // lane l holds feature f = bit-reverse-4(l)
    int f = ((l & 1) << 3) | ((l & 2) << 1) | ((l & 4) >> 1) | ((l & 8) >> 3);
    float di = dinv[i];
    float z = fmaxf(0.f, di * acc[0] + b1[f]);
    float o0 = z * W2[f * 3 + 0];
    float o1 = z * W2[f * 3 + 1];
    float o2 = z * W2[f * 3 + 2];
    #pragma unroll
    for (int m = 1; m < 16; m <<= 1) {
        o0 += __shfl_xor(o0, m);
        o1 += __shfl_xor(o1, m);
        o2 += __shfl_xor(o2, m);
    }
    if (l != 0) return;
    Half4 g;
    g.x = __float2half(di * o0); g.y = __float2half(di * o1);
    g.z = __float2half(di * o2); g.w = __float2half(0.f);
    g2h[i] = g;
}

// ---- gather2: 16 lanes/node edge-split, bias + log_softmax -> out ----
__global__ void k_gather2(const Half4* __restrict__ g2h, const int* __restrict__ csr,
                          const int* __restrict__ row_start, const int* __restrict__ deg,
                          const float* __restrict__ dinv, const float* __restrict__ b2,
                          float* __restrict__ out, int n) {
    int idx = blockIdx.x * 256 + threadIdx.x;
    int i = idx >> 4, l = idx & 15;
    if (i >= n) return;
    int off = row_start[i], dg = deg[i];
    float v0 = 0.f, v1 = 0.f, v2 = 0.f;
    if (l == 0) {
        Half4 s = g2h[i];
        v0 = __half2float(s.x); v1 = __half2float(s.y); v2 = __half2float(s.z);
    }
    for (int e = l; e < dg; e += 16) {
        int s = csr[off + e];
        Half4 g = g2h[s];
        v0 += __half2float(g.x); v1 += __half2float(g.y); v2 += __half2float(g.z);
    }
    #pragma unroll
    for (int o = 1; o < 16; o <<= 1) {
        v0 += __shfl_xor(v0, o);
        v1 += __shfl_xor(v1, o);
        v2 += __shfl_xor(v2, o);
    }
    if (l >= 3) return;
    float di = dinv[i];
    float a0 = di * v0 + b2[0];
    float a1 = di * v1 + b2[1];
    float a2 = di * v2 + b2[2];
    float m = fmaxf(a0, fmaxf(a1, a2));
    float lse = logf(expf(a0 - m) + expf(a1 - m) + expf(a2 - m));
    float r = (l == 0) ? a0 : (l == 1) ? a1 : a2;
    out[(size_t)i * 3 + l] = r - m - lse;
}

// ======================== launch ========================
extern "C" void kernel_launch(void* const* d_in, const int* in_sizes, int n_in,
                              void* d_out, int out_size, void* d_ws, size_t ws_size,
                              hipStream_t stream) {
    const float* x  = (const float*)d_in[0];
    const int*   ei = (const int*)d_in[1];      // [2][E]
    const float* W1 = (const float*)d_in[2];    // [128][16]
    const float* b1 = (const float*)d_in[3];    // [16]
    const float* W2 = (const float*)d_in[4];    // [16][3]
    const float* b2 = (const float*)d_in[5];    // [3]
    float* out = (float*)d_out;

    const int n = in_sizes[0] / 128;   // 100000
    const int E = in_sizes[1] / 2;     // 1600000
    const int* src = ei;
    const int* dst = ei + E;

    const int NBK = (n + BNODES - 1) >> BSH;   // 196

    auto align = [](size_t v) { return (v + 255) & ~(size_t)255; };
    char* ws = (char*)d_ws;
    size_t o = 0;
    int* cursor   = (int*)(ws + o); o = align(o + (size_t)NBK * CSTR * 4);  // line-padded
    int* deg      = (int*)(ws + o); o = align(o + (size_t)n * 4);
    float* dinv   = (float*)(ws + o); o = align(o + (size_t)n * 4);
    int* row_start= (int*)(ws + o); o = align(o + (size_t)n * 4);
    unsigned int* staging = (unsigned int*)(ws + o); o = align(o + (size_t)NBK * BCAP * 4);
    int* csr      = (int*)(ws + o); o = align(o + (size_t)NBK * BCAP * 4);
    Half4* g1h    = (Half4*)(ws + o); o = align(o + (size_t)n * 4 * 8);
    Half4* g2h    = (Half4*)(ws + o); o = align(o + (size_t)n * 8);

    const int B = 256;
    int gGemm = (n + GROWS - 1) / GROWS;   // 1563
    int gn16  = (16 * n + B - 1) / B;      // 6250

    hipMemsetAsync(cursor, 0, (size_t)NBK * CSTR * 4, stream);
    k1b_fat<<<P1 + gGemm, B, 0, stream>>>(src, dst, cursor, staging,
                                          x, W1, g1h, NBK, n, E);
    k2_bucket<<<NBK, 1024, 0, stream>>>(staging, cursor, csr, deg, dinv, row_start, g1h, n);
    k_gather1<<<gn16, B, 0, stream>>>((const uint4*)g1h, csr, row_start, deg, dinv, b1, W2,
                                      g2h, n);
    k_gather2<<<gn16, B, 0, stream>>>(g2h, csr, row_start, deg, dinv, b2, out, n);
}

// Round 14
// 163.606 us; speedup vs baseline: 1.0197x; 1.0197x over previous
//
#include <hip/hip_runtime.h>
#include <hip/hip_fp16.h>
#include <math.h>

// ---------------------------------------------------------------------------
// GCN 2-layer, bucket-partitioned CSR build + wide-parallel fp16 gathers.
// R14: k1b gemm goes LDS-free (partial-K + shfl-halving reduce) -> static LDS
// 42KB -> 29.7KB -> 5 blocks/CU; wave-shfl scans replace barrier scans.
// Pipeline: memset(cursors) -> k1b_fat(scatter||gemm) -> k2 -> g1 -> g2.
// ---------------------------------------------------------------------------

#define BSH 9
#define BNODES 512
#define P1 512
#define GROWS 64     // gemm rows per block
#define K2BUF 10240  // k2 LDS sort buffer entries
#define BCAP 12288   // per-bucket staging/csr capacity (mean 8163, +45 sigma)
#define EPT 16       // max edges per thread in k1b register cache
#define EPT2 12      // max edges per thread in k2 register cache
#define CSTR 16      // cursor stride in ints (64B line padding)

struct alignas(8) Half4 { __half x, y, z, w; };

// ---- k1b FAT: [reg-cached LDS-sorted scatter, dynamic runs] || [gemm1] ----
__global__ void k1b_fat(const int* __restrict__ src, const int* __restrict__ dst,
                        int* __restrict__ cursor,
                        unsigned int* __restrict__ staging,
                        const float* __restrict__ x, const float* __restrict__ W1,
                        Half4* __restrict__ g1h, int NBK, int n, int E) {
    __shared__ int smem[7432];          // 29728 B (scatter uses all; gemm uses 8KB)
    int b = blockIdx.x;
    int t = threadIdx.x;
    if (b < P1) {
        int* hist  = smem;              // [256]
        int* cs    = smem + 256;        // [256]
        int* rbase = smem + 512;        // [256]
        int* cur   = smem + 768;        // [256]
        int* buf   = smem + 1024;       // [3200]
        int* gaddr = smem + 4224;       // [3200]
        int* wsum  = smem + 7424;       // [4]
        hist[t] = 0; cur[t] = 0;
        __syncthreads();
        int slice = (E + P1 - 1) / P1;
        int e0 = b * slice, e1 = min(E, e0 + slice);
        int len = e1 - e0;
        // single global read into registers
        int dl[EPT], sl[EPT];
        int cnt = 0;
        for (int e = e0 + t; e < e1 && cnt < EPT; e += 256, ++cnt) {
            dl[cnt] = dst[e];
            sl[cnt] = src[e];
        }
        for (int i = 0; i < cnt; ++i)
            atomicAdd(&hist[dl[i] >> BSH], 1);
        __syncthreads();
        // wave-shfl inclusive scan over 256 counts (4 waves), then combine
        int h = hist[t];
        int xx = h;
        #pragma unroll
        for (int o = 1; o < 64; o <<= 1) {
            int v = __shfl_up(xx, o);
            if ((t & 63) >= o) xx += v;
        }
        if ((t & 63) == 63) wsum[t >> 6] = xx;
        __syncthreads();
        int wv = t >> 6;
        #pragma unroll
        for (int i = 0; i < 4; ++i)
            if (i < wv) xx += wsum[i];
        cs[t] = xx - h;  // exclusive
        rbase[t] = (h > 0 && t < NBK) ? atomicAdd(&cursor[t * CSTR], h) : 0;
        __syncthreads();
        // place into LDS bucket-sorted; compute global addresses
        for (int i = 0; i < cnt; ++i) {
            int d = dl[i], s = sl[i];
            int k = d >> BSH;
            int tk = atomicAdd(&cur[k], 1);
            int pos = cs[k] + tk;
            buf[pos] = (s << BSH) | (d & (BNODES - 1));
            int g = rbase[k] + tk;
            gaddr[pos] = (g < BCAP) ? (k * BCAP + g) : -1;  // overflow guard
        }
        __syncthreads();
        // coalesced copy-out
        for (int p = t; p < len; p += 256) {
            int a = gaddr[p];
            if (a >= 0) staging[a] = (unsigned int)buf[p];
        }
    } else {
        // ---- gemm: partial-K per lane, shfl-halving reduce, no x staging ----
        float4* sW4 = (float4*)smem;    // [512] = W1 [128][16] as [k][c4]
        for (int i = t; i < 512; i += 256) sW4[i] = ((const float4*)W1)[i];
        __syncthreads();
        int r = t >> 2, c4 = t & 3;
        int row = (b - P1) * GROWS + r;
        if (row >= n) return;           // all 4 lanes of a row exit together
        float acc[16];
        #pragma unroll
        for (int j = 0; j < 16; ++j) acc[j] = 0.f;
        const float4* xr = (const float4*)(x + (size_t)row * 128);
        #pragma unroll
        for (int q = 0; q < 8; ++q) {
            float4 xv = xr[q * 4 + c4];       // cols 16q+4c4 .. +3 (64B segs/wave)
            #pragma unroll
            for (int j = 0; j < 4; ++j) {
                int k = q * 16 + c4 * 4 + j;
                float s = (j == 0) ? xv.x : (j == 1) ? xv.y : (j == 2) ? xv.z : xv.w;
                #pragma unroll
                for (int cq = 0; cq < 4; ++cq) {
                    float4 w = sW4[k * 4 + cq];
                    acc[cq * 4 + 0] += s * w.x; acc[cq * 4 + 1] += s * w.y;
                    acc[cq * 4 + 2] += s * w.z; acc[cq * 4 + 3] += s * w.w;
                }
            }
        }
        // 2-step tree-halving reduce across the 4 row-lanes
        #pragma unroll
        for (int j = 0; j < 8; ++j) {
            float send = (c4 & 1) ? acc[j] : acc[j + 8];
            float recv = __shfl_xor(send, 1);
            acc[j] = ((c4 & 1) ? acc[j + 8] : acc[j]) + recv;
        }
        #pragma unroll
        for (int j = 0; j < 4; ++j) {
            float send = (c4 & 2) ? acc[j] : acc[j + 4];
            float recv = __shfl_xor(send, 2);
            acc[j] = ((c4 & 2) ? acc[j + 4] : acc[j]) + recv;
        }
        // lane c4 holds features base..base+3, base = 8*(c4&1) + 4*((c4&2)>>1)
        int cidx = 2 * (c4 & 1) + ((c4 & 2) >> 1);
        Half4 hh;
        hh.x = __float2half(acc[0]); hh.y = __float2half(acc[1]);
        hh.z = __float2half(acc[2]); hh.w = __float2half(acc[3]);
        g1h[(size_t)row * 4 + cidx] = hh;   // unscaled; k2 applies dinv
    }
}

// ---- k2: per-bucket CSR (reg-cached, wave-scan, contiguous out) + meta ----
__global__ void __launch_bounds__(1024) k2_bucket(
        const unsigned int* __restrict__ staging, const int* __restrict__ cursor,
        int* __restrict__ csr, int* __restrict__ deg, float* __restrict__ dinv,
        int* __restrict__ row_start, Half4* __restrict__ g1h, int n) {
    __shared__ int lh[BNODES], sc[BNODES], lcur[BNODES], wsum[8];
    __shared__ float ldv[BNODES];
    __shared__ int buf[K2BUF];
    int kb = blockIdx.x, t = threadIdx.x;
    int node0 = kb << BSH;
    int nloc = min(BNODES, n - node0);
    int ebase = kb * BCAP;
    int ecnt = min(cursor[kb * CSTR], BCAP);
    if (t < BNODES) { lh[t] = 0; lcur[t] = 0; }
    __syncthreads();
    // single global read into registers
    int el[EPT2];
    int cnt = 0;
    for (int e = t; e < ecnt && cnt < EPT2; e += 1024, ++cnt)
        el[cnt] = (int)staging[ebase + e];
    for (int i = 0; i < cnt; ++i)
        atomicAdd(&lh[el[i] & (BNODES - 1)], 1);
    __syncthreads();
    // wave-shfl inclusive scan over 512 counts (waves 0..7)
    int own = (t < BNODES) ? lh[t] : 0;
    int xx = own;
    #pragma unroll
    for (int o = 1; o < 64; o <<= 1) {
        int v = __shfl_up(xx, o);
        if ((t & 63) >= o) xx += v;
    }
    if (t < BNODES && (t & 63) == 63) wsum[t >> 6] = xx;
    __syncthreads();
    if (t < BNODES) {
        int wv = t >> 6;
        #pragma unroll
        for (int i = 0; i < 8; ++i)
            if (i < wv) xx += wsum[i];
        int excl = xx - own;
        if (t < nloc) {
            deg[node0 + t] = own;
            row_start[node0 + t] = ebase + excl;
            float dv = rsqrtf((float)(own + 1));  // +1 self-loop
            dinv[node0 + t] = dv;
            ldv[t] = dv;
        }
        sc[t] = excl;
    }
    __syncthreads();
    if (ecnt <= K2BUF) {
        for (int i = 0; i < cnt; ++i) {
            int p = el[i];
            int loc = p & (BNODES - 1);
            int tk = atomicAdd(&lcur[loc], 1);
            buf[sc[loc] + tk] = p >> BSH;
        }
        __syncthreads();
        for (int p = t; p < ecnt; p += 1024)
            csr[ebase + p] = buf[p];
    } else {  // statistically unreachable fallback
        for (int i = 0; i < cnt; ++i) {
            int p = el[i];
            int loc = p & (BNODES - 1);
            int tk = atomicAdd(&lcur[loc], 1);
            csr[ebase + sc[loc] + tk] = p >> BSH;
        }
    }
    for (int j = t; j < nloc * 4; j += 1024) {
        float dv = ldv[j >> 2];
        Half4 v = g1h[(size_t)node0 * 4 + j];
        v.x = __float2half(__half2float(v.x) * dv);
        v.y = __float2half(__half2float(v.y) * dv);
        v.z = __float2half(__half2float(v.z) * dv);
        v.w = __float2half(__half2float(v.w) * dv);
        g1h[(size_t)node0 * 4 + j] = v;
    }
}

// ---- gather1: 16 lanes/node, 32B msg per lane-edge, tree-halving reduce ----
__global__ void k_gather1(const uint4* __restrict__ g1q, const int* __restrict__ csr,
                          const int* __restrict__ row_start, const int* __restrict__ deg,
                          const float* __restrict__ dinv, const float* __restrict__ b1,
                          const float* __restrict__ W2, Half4* __restrict__ g2h, int n) {
    int idx = blockIdx.x * 256 + threadIdx.x;
    int i = idx >> 4, l = idx & 15;
    if (i >= n) return;
    int off = row_start[i], dg = deg[i];
    float acc[16];
    #pragma unroll
    for (int j = 0; j < 16; ++j) acc[j] = 0.f;
    if (l == 0) {   // self-loop term (32 B = g1q[2i], g1q[2i+1])
        uint4 p0 = g1q[2 * (size_t)i], p1 = g1q[2 * (size_t)i + 1];
        const __half2* h0 = reinterpret_cast<const __half2*>(&p0);
        const __half2* h1 = reinterpret_cast<const __half2*>(&p1);
        #pragma unroll
        for (int j = 0; j < 4; ++j) {
            float2 f0 = __half22float2(h0[j]);
            float2 f1 = __half22float2(h1[j]);
            acc[2 * j] += f0.x; acc[2 * j + 1] += f0.y;
            acc[8 + 2 * j] += f1.x; acc[9 + 2 * j] += f1.y;
        }
    }
    for (int k = l; k < dg; k += 16) {
        int s = csr[off + k];
        uint4 p0 = g1q[2 * (size_t)s], p1 = g1q[2 * (size_t)s + 1];
        const __half2* h0 = reinterpret_cast<const __half2*>(&p0);
        const __half2* h1 = reinterpret_cast<const __half2*>(&p1);
        #pragma unroll
        for (int j = 0; j < 4; ++j) {
            float2 f0 = __half22float2(h0[j]);
            float2 f1 = __half22float2(h1[j]);
            acc[2 * j] += f0.x; acc[2 * j + 1] += f0.y;
            acc[8 + 2 * j] += f1.x; acc[9 + 2 * j] += f1.y;
        }
    }
    // tree-halving cross-lane reduce
    #pragma unroll
    for (int j = 0; j < 8; ++j) {
        float send = (l & 1) ? acc[j] : acc[j + 8];
        float recv = __shfl_xor(send, 1);
        acc[j] = ((l & 1) ? acc[j + 8] : acc[j]) + recv;
    }
    #pragma unroll
    for (int j = 0; j < 4; ++j) {
        float send = (l & 2) ? acc[j] : acc[j + 4];
        float recv = __shfl_xor(send, 2);
        acc[j] = ((l & 2) ? acc[j + 4] : acc[j]) + recv;
    }
    #pragma unroll
    for (int j = 0; j < 2; ++j) {
        float send = (l & 4) ? acc[j] : acc[j + 2];
        float recv = __shfl_xor(send, 4);
        acc[j] = ((l & 4) ? acc[j + 2] : acc[j]) + recv;
    }
    {
        float send = (l & 8) ? acc[0] : acc[1];
        float recv = __shfl_xor(send, 8);
        acc[0] = ((l & 8) ? acc[1] : acc[0]) + recv;
    }
    // lane l holds feature f = bit-reverse-4(l)
    int f = ((l & 1) << 3) | ((l & 2) << 1) | ((l & 4) >> 1) | ((l & 8) >> 3);
    float di = dinv[i];
    float z = fmaxf(0.f, di * acc[0] + b1[f]);
    float o0 = z * W2[f * 3 + 0];
    float o1 = z * W2[f * 3 + 1];
    float o2 = z * W2[f * 3 + 2];
    #pragma unroll
    for (int m = 1; m < 16; m <<= 1) {
        o0 += __shfl_xor(o0, m);
        o1 += __shfl_xor(o1, m);
        o2 += __shfl_xor(o2, m);
    }
    if (l != 0) return;
    Half4 g;
    g.x = __float2half(di * o0); g.y = __float2half(di * o1);
    g.z = __float2half(di * o2); g.w = __float2half(0.f);
    g2h[i] = g;
}

// ---- gather2: 16 lanes/node edge-split, bias + log_softmax -> out ----
__global__ void k_gather2(const Half4* __restrict__ g2h, const int* __restrict__ csr,
                          const int* __restrict__ row_start, const int* __restrict__ deg,
                          const float* __restrict__ dinv, const float* __restrict__ b2,
                          float* __restrict__ out, int n) {
    int idx = blockIdx.x * 256 + threadIdx.x;
    int i = idx >> 4, l = idx & 15;
    if (i >= n) return;
    int off = row_start[i], dg = deg[i];
    float v0 = 0.f, v1 = 0.f, v2 = 0.f;
    if (l == 0) {
        Half4 s = g2h[i];
        v0 = __half2float(s.x); v1 = __half2float(s.y); v2 = __half2float(s.z);
    }
    for (int e = l; e < dg; e += 16) {
        int s = csr[off + e];
        Half4 g = g2h[s];
        v0 += __half2float(g.x); v1 += __half2float(g.y); v2 += __half2float(g.z);
    }
    #pragma unroll
    for (int o = 1; o < 16; o <<= 1) {
        v0 += __shfl_xor(v0, o);
        v1 += __shfl_xor(v1, o);
        v2 += __shfl_xor(v2, o);
    }
    if (l >= 3) return;
    float di = dinv[i];
    float a0 = di * v0 + b2[0];
    float a1 = di * v1 + b2[1];
    float a2 = di * v2 + b2[2];
    float m = fmaxf(a0, fmaxf(a1, a2));
    float lse = logf(expf(a0 - m) + expf(a1 - m) + expf(a2 - m));
    float r = (l == 0) ? a0 : (l == 1) ? a1 : a2;
    out[(size_t)i * 3 + l] = r - m - lse;
}

// ======================== launch ========================
extern "C" void kernel_launch(void* const* d_in, const int* in_sizes, int n_in,
                              void* d_out, int out_size, void* d_ws, size_t ws_size,
                              hipStream_t stream) {
    const float* x  = (const float*)d_in[0];
    const int*   ei = (const int*)d_in[1];      // [2][E]
    const float* W1 = (const float*)d_in[2];    // [128][16]
    const float* b1 = (const float*)d_in[3];    // [16]
    const float* W2 = (const float*)d_in[4];    // [16][3]
    const float* b2 = (const float*)d_in[5];    // [3]
    float* out = (float*)d_out;

    const int n = in_sizes[0] / 128;   // 100000
    const int E = in_sizes[1] / 2;     // 1600000
    const int* src = ei;
    const int* dst = ei + E;

    const int NBK = (n + BNODES - 1) >> BSH;   // 196

    auto align = [](size_t v) { return (v + 255) & ~(size_t)255; };
    char* ws = (char*)d_ws;
    size_t o = 0;
    int* cursor   = (int*)(ws + o); o = align(o + (size_t)NBK * CSTR * 4);
    int* deg      = (int*)(ws + o); o = align(o + (size_t)n * 4);
    float* dinv   = (float*)(ws + o); o = align(o + (size_t)n * 4);
    int* row_start= (int*)(ws + o); o = align(o + (size_t)n * 4);
    unsigned int* staging = (unsigned int*)(ws + o); o = align(o + (size_t)NBK * BCAP * 4);
    int* csr      = (int*)(ws + o); o = align(o + (size_t)NBK * BCAP * 4);
    Half4* g1h    = (Half4*)(ws + o); o = align(o + (size_t)n * 4 * 8);
    Half4* g2h    = (Half4*)(ws + o); o = align(o + (size_t)n * 8);

    const int B = 256;
    int gGemm = (n + GROWS - 1) / GROWS;   // 1563
    int gn16  = (16 * n + B - 1) / B;      // 6250

    hipMemsetAsync(cursor, 0, (size_t)NBK * CSTR * 4, stream);
    k1b_fat<<<P1 + gGemm, B, 0, stream>>>(src, dst, cursor, staging,
                                          x, W1, g1h, NBK, n, E);
    k2_bucket<<<NBK, 1024, 0, stream>>>(staging, cursor, csr, deg, dinv, row_start, g1h, n);
    k_gather1<<<gn16, B, 0, stream>>>((const uint4*)g1h, csr, row_start, deg, dinv, b1, W2,
                                      g2h, n);
    k_gather2<<<gn16, B, 0, stream>>>(g2h, csr, row_start, deg, dinv, b2, out, n);
}